// Round 2
// baseline (373.661 us; speedup 1.0000x reference)
//
#include <hip/hip_runtime.h>

#define BN 16384   // B*N rows
#define NN 2048    // N
#define DD 64      // hidden
#define CC 16      // classes

// ---------------- threefry-2x32 dropout mask (JAX key(42)) ----------------
// Modern JAX (jax_threefry_partitionable=True, default since 0.4.36):
// per-element counter i (uint64) -> x0 = hi32(i) = 0, x1 = lo32(i) = i,
// threefry2x32 with key (0,42), 32-bit output = out_x0 ^ out_x1.
// uniform<0.5 reduces to bit31(output)==0.
__device__ __forceinline__ unsigned tf_bits(unsigned i) {
  unsigned x0 = 0u;
  unsigned x1 = i;
  const unsigned k0 = 0u, k1 = 42u, k2 = 0x1BD11BDAu ^ 0u ^ 42u;
  x0 += k0; x1 += k1;
#define TFR(r) { x0 += x1; x1 = (x1 << (r)) | (x1 >> (32 - (r))); x1 ^= x0; }
  TFR(13) TFR(15) TFR(26) TFR(6)
  x0 += k1; x1 += k2 + 1u;
  TFR(17) TFR(29) TFR(16) TFR(24)
  x0 += k2; x1 += k0 + 2u;
  TFR(13) TFR(15) TFR(26) TFR(6)
  x0 += k0; x1 += k1 + 3u;
  TFR(17) TFR(29) TFR(16) TFR(24)
  x0 += k1; x1 += k2 + 4u;
  TFR(13) TFR(15) TFR(26) TFR(6)
  x0 += k2; x1 += k0 + 5u;
#undef TFR
  return x0 ^ x1;
}

// ------------- kernel 1: degrees + Y1s = dis * (X @ W1) -------------------
// wave per row; lane sums row of A (float4 x8), xor-reduce; then lane=c of X@W1.
__global__ __launch_bounds__(256) void k_deg_xw(const float* __restrict__ A,
    const float* __restrict__ X, const float* __restrict__ W1,
    float* __restrict__ dis, float* __restrict__ Y1s)
{
  const int w = threadIdx.x >> 6, lane = threadIdx.x & 63;
  const int row = __builtin_amdgcn_readfirstlane(blockIdx.x * 4 + w);
  const float4* Arow = (const float4*)(A + (size_t)row * NN);
  float s = 0.f;
#pragma unroll
  for (int it = 0; it < 8; ++it) {
    float4 v = Arow[lane + 64 * it];
    s += v.x + v.y + v.z + v.w;
  }
#pragma unroll
  for (int m = 32; m; m >>= 1) s += __shfl_xor(s, m, 64);
  const float dv = 1.0f / sqrtf(s + 1.0f);   // A_tilda = A + I
  if (lane == 0) dis[row] = dv;
  const float* Xr = X + (size_t)row * DD;    // wave-uniform -> scalar loads
  float acc = 0.f;
#pragma unroll
  for (int k = 0; k < DD; ++k) acc += Xr[k] * W1[k * DD + lane];
  Y1s[(size_t)row * DD + lane] = dv * acc;
}

// ------------- kernel 2: Z1[part] = A @ Y1s (per K-half) ------------------
// block: 4 waves; wave w handles cols [16w,16w+16); lane = row within 64-row tile.
// A streamed float4/lane (prefetched); Y via wave-uniform scalar loads.
__global__ __launch_bounds__(256) void k_gemm1(const float* __restrict__ A,
    const float* __restrict__ Y1s, float* __restrict__ Z1)
{
  const int rb   = blockIdx.x >> 1;                 // 0..255 (64-row tiles)
  const int ks   = blockIdx.x & 1;                  // K half
  const int lane = threadIdx.x & 63;
  const int c0   = __builtin_amdgcn_readfirstlane((threadIdx.x >> 6) << 4);
  const int row  = rb * 64 + lane;
  const int batch = rb >> 5;                        // uniform (from blockIdx)
  const float* Arow = A + (size_t)row * NN + ks * 1024;
  const float* Yb = Y1s + (size_t)batch * NN * DD + c0;
  const int kbase = ks * 1024;
  float acc[16];
#pragma unroll
  for (int c = 0; c < 16; ++c) acc[c] = 0.f;
  float4 a0 = *(const float4*)(Arow);
  float4 a1 = *(const float4*)(Arow + 4);
  for (int k = 0; k < 1024; k += 8) {
    const int kn = (k + 8 < 1024) ? (k + 8) : 0;    // wrap: safe re-read
    float4 n0 = *(const float4*)(Arow + kn);
    float4 n1 = *(const float4*)(Arow + kn + 4);
    const float* y0 = Yb + (size_t)(kbase + k) * DD;
    const float av[8] = {a0.x, a0.y, a0.z, a0.w, a1.x, a1.y, a1.z, a1.w};
#pragma unroll
    for (int j = 0; j < 8; ++j) {
      const float* yr = y0 + j * DD;                // uniform -> s_load_dwordx16
#pragma unroll
      for (int c = 0; c < 16; ++c) acc[c] += av[j] * yr[c];
    }
    a0 = n0; a1 = n1;
  }
  float* Zp = Z1 + ((size_t)ks * BN + row) * DD + c0;
#pragma unroll
  for (int c = 0; c < 16; c += 4) {
    float4 v; v.x = acc[c]; v.y = acc[c+1]; v.z = acc[c+2]; v.w = acc[c+3];
    *(float4*)(Zp + c) = v;
  }
}

// ------------- kernel 3: h = dropout(relu(...)); Y2s = dis*(h@W2) ---------
__global__ __launch_bounds__(256) void k_epi1(const float* __restrict__ Z1,
    const float* __restrict__ Y1s, const float* __restrict__ dis,
    const float* __restrict__ b1, const float* __restrict__ W2,
    float* __restrict__ Y2s)
{
  __shared__ float W2l[DD * CC];
  __shared__ float hl[4][DD];
  const int tid = threadIdx.x;
  *(float4*)(W2l + tid * 4) = *(const float4*)(W2 + tid * 4);  // stage W2
  const int w = tid >> 6, lane = tid & 63;
  const int row = blockIdx.x * 4 + w;
  const size_t o = (size_t)row * DD + lane;
  const float z = Z1[o] + Z1[(size_t)BN * DD + o] + Y1s[o];
  const float dv = dis[row];
  float h = fmaxf(dv * z + b1[lane], 0.f);
  const unsigned bits = tf_bits((unsigned)o);
  h = (bits >> 31) ? 0.f : (h + h);                 // dropout p=0.5, scale 2
  hl[w][lane] = h;
  __syncthreads();
  // h @ W2: 4 rows x 16 cols, 4-way k-split across lanes + shuffle reduce
  const int wr = tid >> 6, l = tid & 63;
  const int c = l & 15, kq = l >> 4;
  float p = 0.f;
#pragma unroll
  for (int kk = 0; kk < 16; ++kk)
    p += hl[wr][kq * 16 + kk] * W2l[(kq * 16 + kk) * CC + c];
  p += __shfl_xor(p, 16, 64);
  p += __shfl_xor(p, 32, 64);
  if (l < 16) {
    const int rg = blockIdx.x * 4 + wr;
    Y2s[(size_t)rg * CC + c] = dis[rg] * p;
  }
}

// ------------- kernel 4: Z2[part] = A @ Y2s (8-way K-split) ---------------
__global__ __launch_bounds__(256) void k_gemm2(const float* __restrict__ A,
    const float* __restrict__ Y2s, float* __restrict__ Z2)
{
  const int rb = blockIdx.x >> 3;                   // 0..63 (256-row tiles)
  const int ks = blockIdx.x & 7;
  const int row = rb * 256 + threadIdx.x;
  const int batch = rb >> 3;                        // uniform
  const float* Arow = A + (size_t)row * NN + ks * 256;
  const float* Yb = Y2s + (size_t)batch * NN * CC;
  const int kbase = ks * 256;
  float acc[16];
#pragma unroll
  for (int c = 0; c < 16; ++c) acc[c] = 0.f;
  float4 a0 = *(const float4*)(Arow);
  float4 a1 = *(const float4*)(Arow + 4);
  for (int k = 0; k < 256; k += 8) {
    const int kn = (k + 8 < 256) ? (k + 8) : 0;
    float4 n0 = *(const float4*)(Arow + kn);
    float4 n1 = *(const float4*)(Arow + kn + 4);
    const float av[8] = {a0.x, a0.y, a0.z, a0.w, a1.x, a1.y, a1.z, a1.w};
#pragma unroll
    for (int j = 0; j < 8; ++j) {
      const float* yr = Yb + (size_t)(kbase + k + j) * CC;  // uniform s_load
#pragma unroll
      for (int c = 0; c < 16; ++c) acc[c] += av[j] * yr[c];
    }
    a0 = n0; a1 = n1;
  }
  float* Zp = Z2 + ((size_t)ks * BN + row) * CC;
#pragma unroll
  for (int c = 0; c < 16; c += 4) {
    float4 v; v.x = acc[c]; v.y = acc[c+1]; v.z = acc[c+2]; v.w = acc[c+3];
    *(float4*)(Zp + c) = v;
  }
}

// ------------- kernel 5: out = dis*(sum Z2p + Y2s) + b2 -------------------
__global__ __launch_bounds__(256) void k_final(const float* __restrict__ Z2,
    const float* __restrict__ Y2s, const float* __restrict__ dis,
    const float* __restrict__ b2, float* __restrict__ out)
{
  const int gid = blockIdx.x * 256 + threadIdx.x;   // 65536 float4 groups
  const int r = gid >> 2, q = gid & 3;
  const size_t o = (size_t)r * CC + q * 4;
  float4 s = *(const float4*)(Y2s + o);
#pragma unroll
  for (int p = 0; p < 8; ++p) {
    const float4 zp = *(const float4*)(Z2 + (size_t)p * BN * CC + o);
    s.x += zp.x; s.y += zp.y; s.z += zp.z; s.w += zp.w;
  }
  const float dv = dis[r];
  const float4 bb = *(const float4*)(b2 + q * 4);
  float4 res;
  res.x = dv * s.x + bb.x;
  res.y = dv * s.y + bb.y;
  res.z = dv * s.z + bb.z;
  res.w = dv * s.w + bb.w;
  *(float4*)(out + o) = res;
}

extern "C" void kernel_launch(void* const* d_in, const int* in_sizes, int n_in,
                              void* d_out, int out_size, void* d_ws, size_t ws_size,
                              hipStream_t stream) {
  const float* X  = (const float*)d_in[0];
  const float* A  = (const float*)d_in[1];
  const float* W1 = (const float*)d_in[2];
  const float* b1 = (const float*)d_in[3];
  const float* W2 = (const float*)d_in[4];
  const float* b2 = (const float*)d_in[5];
  float* out = (float*)d_out;

  // ws layout (floats), ~13.1 MB total; Z2 aliases Z1 (dead after k_epi1)
  float* ws  = (float*)d_ws;
  float* dis = ws;                       // 16384
  float* Y1s = ws + 16384;               // 1048576
  float* Z1  = Y1s + (size_t)BN * DD;    // 2 x 1048576 (8 MB)
  float* Z2  = Z1;                       // 8 x 262144  (same 8 MB, reused)
  float* Y2s = Z1 + (size_t)2 * BN * DD; // 262144

  k_deg_xw<<<BN / 4, 256, 0, stream>>>(A, X, W1, dis, Y1s);
  k_gemm1 <<<512,    256, 0, stream>>>(A, Y1s, Z1);
  k_epi1  <<<BN / 4, 256, 0, stream>>>(Z1, Y1s, dis, b1, W2, Y2s);
  k_gemm2 <<<512,    256, 0, stream>>>(A, Y2s, Z2);
  k_final <<<256,    256, 0, stream>>>(Z2, Y2s, dis, b2, out);
}

// Round 3
// 350.179 us; speedup vs baseline: 1.0671x; 1.0671x over previous
//
#include <hip/hip_runtime.h>

#define BN 16384   // B*N rows
#define NN 2048    // N
#define DD 64      // hidden
#define CC 16      // classes
#define KS1 4      // K-splits layer-1 gemm (512 K each)
#define KS2 16     // K-splits layer-2 gemm (128 K each)

// ---------------- threefry-2x32 dropout mask (JAX key(42)) ----------------
// partitionable=True path: counter i -> x0=0, x1=i, key (0,42); out = x0^x1;
// keep iff bit31==0.
__device__ __forceinline__ unsigned tf_bits(unsigned i) {
  unsigned x0 = 0u;
  unsigned x1 = i;
  const unsigned k0 = 0u, k1 = 42u, k2 = 0x1BD11BDAu ^ 0u ^ 42u;
  x0 += k0; x1 += k1;
#define TFR(r) { x0 += x1; x1 = (x1 << (r)) | (x1 >> (32 - (r))); x1 ^= x0; }
  TFR(13) TFR(15) TFR(26) TFR(6)
  x0 += k1; x1 += k2 + 1u;
  TFR(17) TFR(29) TFR(16) TFR(24)
  x0 += k2; x1 += k0 + 2u;
  TFR(13) TFR(15) TFR(26) TFR(6)
  x0 += k0; x1 += k1 + 3u;
  TFR(17) TFR(29) TFR(16) TFR(24)
  x0 += k1; x1 += k2 + 4u;
  TFR(13) TFR(15) TFR(26) TFR(6)
  x0 += k2; x1 += k0 + 5u;
#undef TFR
  return x0 ^ x1;
}

// ------------- kernel 1: degrees + Y1s = dis * (X @ W1) -------------------
__global__ __launch_bounds__(256) void k_deg_xw(const float* __restrict__ A,
    const float* __restrict__ X, const float* __restrict__ W1,
    float* __restrict__ dis, float* __restrict__ Y1s)
{
  const int w = threadIdx.x >> 6, lane = threadIdx.x & 63;
  const int row = __builtin_amdgcn_readfirstlane(blockIdx.x * 4 + w);
  const float4* Arow = (const float4*)(A + (size_t)row * NN);
  float s = 0.f;
#pragma unroll
  for (int it = 0; it < 8; ++it) {
    float4 v = Arow[lane + 64 * it];
    s += v.x + v.y + v.z + v.w;
  }
#pragma unroll
  for (int m = 32; m; m >>= 1) s += __shfl_xor(s, m, 64);
  const float dv = 1.0f / sqrtf(s + 1.0f);   // A_tilda = A + I
  if (lane == 0) dis[row] = dv;
  const float* Xr = X + (size_t)row * DD;    // wave-uniform -> scalar loads
  float acc = 0.f;
#pragma unroll
  for (int k = 0; k < DD; ++k) acc += Xr[k] * W1[k * DD + lane];
  Y1s[(size_t)row * DD + lane] = dv * acc;
}

// ------------- kernel 2: Z1[part] = A @ Y1s (KS1-way K-split) -------------
// block: 4 waves; wave w -> cols [16w,16w+16); lane = row within 64-row tile.
// A streamed float4/lane (prefetched); Y via wave-uniform scalar loads.
// J=16 unroll: 16 s_loads (64B each) feed 256 FMAs.
__global__ __launch_bounds__(256) void k_gemm1(const float* __restrict__ A,
    const float* __restrict__ Y1s, float* __restrict__ Z1)
{
  const int rb   = blockIdx.x >> 2;                 // 0..255 (64-row tiles)
  const int ks   = blockIdx.x & (KS1 - 1);          // K quarter
  const int lane = threadIdx.x & 63;
  const int c0   = __builtin_amdgcn_readfirstlane((threadIdx.x >> 6) << 4);
  const int row  = rb * 64 + lane;
  const int batch = rb >> 5;                        // uniform (from blockIdx)
  const int KSEG = NN / KS1;                        // 512
  const float* Arow = A + (size_t)row * NN + ks * KSEG;
  const float* Yb = Y1s + (size_t)batch * NN * DD + c0;
  const int kbase = ks * KSEG;
  float acc[16];
#pragma unroll
  for (int c = 0; c < 16; ++c) acc[c] = 0.f;
  float4 a0 = *(const float4*)(Arow);
  float4 a1 = *(const float4*)(Arow + 4);
  float4 a2 = *(const float4*)(Arow + 8);
  float4 a3 = *(const float4*)(Arow + 12);
  for (int k = 0; k < KSEG; k += 16) {
    const int kn = (k + 16 < KSEG) ? (k + 16) : 0;  // wrap: safe re-read
    float4 n0 = *(const float4*)(Arow + kn);
    float4 n1 = *(const float4*)(Arow + kn + 4);
    float4 n2 = *(const float4*)(Arow + kn + 8);
    float4 n3 = *(const float4*)(Arow + kn + 12);
    const float* y0 = Yb + (size_t)(kbase + k) * DD;
    const float av[16] = {a0.x, a0.y, a0.z, a0.w, a1.x, a1.y, a1.z, a1.w,
                          a2.x, a2.y, a2.z, a2.w, a3.x, a3.y, a3.z, a3.w};
#pragma unroll
    for (int j = 0; j < 16; ++j) {
      const float* yr = y0 + j * DD;                // uniform -> s_load_dwordx16
#pragma unroll
      for (int c = 0; c < 16; ++c) acc[c] += av[j] * yr[c];
    }
    a0 = n0; a1 = n1; a2 = n2; a3 = n3;
  }
  float* Zp = Z1 + ((size_t)ks * BN + row) * DD + c0;
#pragma unroll
  for (int c = 0; c < 16; c += 4) {
    float4 v; v.x = acc[c]; v.y = acc[c+1]; v.z = acc[c+2]; v.w = acc[c+3];
    *(float4*)(Zp + c) = v;
  }
}

// ------------- kernel 3: h = dropout(relu(...)); Y2s = dis*(h@W2) ---------
__global__ __launch_bounds__(256) void k_epi1(const float* __restrict__ Z1,
    const float* __restrict__ Y1s, const float* __restrict__ dis,
    const float* __restrict__ b1, const float* __restrict__ W2,
    float* __restrict__ Y2s)
{
  __shared__ float W2l[DD * CC];
  __shared__ float hl[4][DD];
  const int tid = threadIdx.x;
  *(float4*)(W2l + tid * 4) = *(const float4*)(W2 + tid * 4);  // stage W2
  const int w = tid >> 6, lane = tid & 63;
  const int row = blockIdx.x * 4 + w;
  const size_t o = (size_t)row * DD + lane;
  float z = Y1s[o];
#pragma unroll
  for (int p = 0; p < KS1; ++p) z += Z1[(size_t)p * BN * DD + o];
  const float dv = dis[row];
  float h = fmaxf(dv * z + b1[lane], 0.f);
  const unsigned bits = tf_bits((unsigned)o);
  h = (bits >> 31) ? 0.f : (h + h);                 // dropout p=0.5, scale 2
  hl[w][lane] = h;
  __syncthreads();
  // h @ W2: 4 rows x 16 cols, 4-way k-split across lanes + shuffle reduce
  const int wr = tid >> 6, l = tid & 63;
  const int c = l & 15, kq = l >> 4;
  float p = 0.f;
#pragma unroll
  for (int kk = 0; kk < 16; ++kk)
    p += hl[wr][kq * 16 + kk] * W2l[(kq * 16 + kk) * CC + c];
  p += __shfl_xor(p, 16, 64);
  p += __shfl_xor(p, 32, 64);
  if (l < 16) {
    const int rg = blockIdx.x * 4 + wr;
    Y2s[(size_t)rg * CC + c] = dis[rg] * p;
  }
}

// ------------- kernel 4: Z2[part] = A @ Y2s (KS2-way K-split) -------------
__global__ __launch_bounds__(256) void k_gemm2(const float* __restrict__ A,
    const float* __restrict__ Y2s, float* __restrict__ Z2)
{
  const int rb = blockIdx.x >> 4;                   // 0..63 (256-row tiles)
  const int ks = blockIdx.x & (KS2 - 1);
  const int row = rb * 256 + threadIdx.x;
  const int batch = rb >> 3;                        // uniform
  const int KSEG = NN / KS2;                        // 128
  const float* Arow = A + (size_t)row * NN + ks * KSEG;
  const float* Yb = Y2s + (size_t)batch * NN * CC;
  const int kbase = ks * KSEG;
  float acc[16];
#pragma unroll
  for (int c = 0; c < 16; ++c) acc[c] = 0.f;
  float4 a0 = *(const float4*)(Arow);
  float4 a1 = *(const float4*)(Arow + 4);
  for (int k = 0; k < KSEG; k += 8) {
    const int kn = (k + 8 < KSEG) ? (k + 8) : 0;
    float4 n0 = *(const float4*)(Arow + kn);
    float4 n1 = *(const float4*)(Arow + kn + 4);
    const float av[8] = {a0.x, a0.y, a0.z, a0.w, a1.x, a1.y, a1.z, a1.w};
#pragma unroll
    for (int j = 0; j < 8; ++j) {
      const float* yr = Yb + (size_t)(kbase + k + j) * CC;  // uniform s_load
#pragma unroll
      for (int c = 0; c < 16; ++c) acc[c] += av[j] * yr[c];
    }
    a0 = n0; a1 = n1;
  }
  float* Zp = Z2 + ((size_t)ks * BN + row) * CC;
#pragma unroll
  for (int c = 0; c < 16; c += 4) {
    float4 v; v.x = acc[c]; v.y = acc[c+1]; v.z = acc[c+2]; v.w = acc[c+3];
    *(float4*)(Zp + c) = v;
  }
}

// ------------- kernel 5: out = dis*(sum Z2p + Y2s) + b2 -------------------
__global__ __launch_bounds__(256) void k_final(const float* __restrict__ Z2,
    const float* __restrict__ Y2s, const float* __restrict__ dis,
    const float* __restrict__ b2, float* __restrict__ out)
{
  const int gid = blockIdx.x * 256 + threadIdx.x;   // 65536 float4 groups
  const int r = gid >> 2, q = gid & 3;
  const size_t o = (size_t)r * CC + q * 4;
  float4 s = *(const float4*)(Y2s + o);
#pragma unroll
  for (int p = 0; p < KS2; ++p) {
    const float4 zp = *(const float4*)(Z2 + (size_t)p * BN * CC + o);
    s.x += zp.x; s.y += zp.y; s.z += zp.z; s.w += zp.w;
  }
  const float dv = dis[r];
  const float4 bb = *(const float4*)(b2 + q * 4);
  float4 res;
  res.x = dv * s.x + bb.x;
  res.y = dv * s.y + bb.y;
  res.z = dv * s.z + bb.z;
  res.w = dv * s.w + bb.w;
  *(float4*)(out + o) = res;
}

extern "C" void kernel_launch(void* const* d_in, const int* in_sizes, int n_in,
                              void* d_out, int out_size, void* d_ws, size_t ws_size,
                              hipStream_t stream) {
  const float* X  = (const float*)d_in[0];
  const float* A  = (const float*)d_in[1];
  const float* W1 = (const float*)d_in[2];
  const float* b1 = (const float*)d_in[3];
  const float* W2 = (const float*)d_in[4];
  const float* b2 = (const float*)d_in[5];
  float* out = (float*)d_out;

  // ws layout (floats), ~21.1 MB; Z2 partials alias Z1 (dead after k_epi1)
  float* ws  = (float*)d_ws;
  float* dis = ws;                       // 16384
  float* Y1s = ws + 16384;               // 1048576 (4 MB)
  float* Z1  = Y1s + (size_t)BN * DD;    // KS1 x 1048576 (16 MB)
  float* Z2  = Z1;                       // KS2 x 262144  (16 MB, reused)
  float* Y2s = Z1 + (size_t)KS1 * BN * DD; // 262144 (1 MB)

  k_deg_xw<<<BN / 4,    256, 0, stream>>>(A, X, W1, dis, Y1s);
  k_gemm1 <<<256 * KS1, 256, 0, stream>>>(A, Y1s, Z1);
  k_epi1  <<<BN / 4,    256, 0, stream>>>(Z1, Y1s, dis, b1, W2, Y2s);
  k_gemm2 <<<64 * KS2,  256, 0, stream>>>(A, Y2s, Z2);
  k_final <<<256,       256, 0, stream>>>(Z2, Y2s, dis, b2, out);
}

// Round 4
// 277.492 us; speedup vs baseline: 1.3466x; 1.2619x over previous
//
#include <hip/hip_runtime.h>

#define BN 16384   // B*N rows
#define NN 2048    // N
#define DD 64      // hidden
#define CC 16      // classes

typedef short bf16x8 __attribute__((ext_vector_type(8)));
typedef float f32x4 __attribute__((ext_vector_type(4)));
typedef unsigned short u16x4 __attribute__((ext_vector_type(4)));

__device__ __forceinline__ f32x4 mfma16(bf16x8 a, bf16x8 b, f32x4 c) {
  return __builtin_amdgcn_mfma_f32_16x16x32_bf16(a, b, c, 0, 0, 0);
}
__device__ __forceinline__ unsigned short f2bf(float f) {   // RNE
  unsigned u = __float_as_uint(f);
  return (unsigned short)((u + 0x7FFFu + ((u >> 16) & 1u)) >> 16);
}
__device__ __forceinline__ float bf2f(unsigned short h) {
  return __uint_as_float(((unsigned)h) << 16);
}

// ---------------- threefry-2x32 dropout mask (JAX key(42)) ----------------
// partitionable path: counter i -> x0=0, x1=i, key (0,42); out = x0^x1;
// keep iff bit31==0.
__device__ __forceinline__ unsigned tf_bits(unsigned i) {
  unsigned x0 = 0u;
  unsigned x1 = i;
  const unsigned k0 = 0u, k1 = 42u, k2 = 0x1BD11BDAu ^ 0u ^ 42u;
  x0 += k0; x1 += k1;
#define TFR(r) { x0 += x1; x1 = (x1 << (r)) | (x1 >> (32 - (r))); x1 ^= x0; }
  TFR(13) TFR(15) TFR(26) TFR(6)
  x0 += k1; x1 += k2 + 1u;
  TFR(17) TFR(29) TFR(16) TFR(24)
  x0 += k2; x1 += k0 + 2u;
  TFR(13) TFR(15) TFR(26) TFR(6)
  x0 += k0; x1 += k1 + 3u;
  TFR(17) TFR(29) TFR(16) TFR(24)
  x0 += k1; x1 += k2 + 4u;
  TFR(13) TFR(15) TFR(26) TFR(6)
  x0 += k2; x1 += k0 + 5u;
#undef TFR
  return x0 ^ x1;
}

// ==================== NEW bf16-MFMA PATH ====================

// ---- k_deg: row degrees + A -> bf16 conversion (single pass over A) ------
__global__ __launch_bounds__(256) void k_deg(const float* __restrict__ A,
    float* __restrict__ dis, unsigned short* __restrict__ Abf)
{
  const int w = threadIdx.x >> 6, lane = threadIdx.x & 63;
  const size_t row = (size_t)blockIdx.x * 4 + w;
  const float4* Arow = (const float4*)(A + row * NN);
  unsigned short* Brow = Abf + row * NN;
  float s = 0.f;
#pragma unroll
  for (int it = 0; it < 8; ++it) {
    float4 v = Arow[lane + 64 * it];
    s += (v.x + v.y) + (v.z + v.w);
    u16x4 p = { f2bf(v.x), f2bf(v.y), f2bf(v.z), f2bf(v.w) };
    *(u16x4*)(Brow + lane * 4 + it * 256) = p;
  }
#pragma unroll
  for (int m = 32; m; m >>= 1) s += __shfl_xor(s, m, 64);
  if (lane == 0) dis[row] = 1.0f / sqrtf(s + 1.0f);   // A_tilda = A + I
}

// ---- k_xw1: Y1 = dis * (X @ W1); store row-major bf16 + transposed bf16 --
__global__ __launch_bounds__(256) void k_xw1(const float* __restrict__ X,
    const float* __restrict__ W1, const float* __restrict__ dis,
    unsigned short* __restrict__ Y1s, unsigned short* __restrict__ Y1sT)
{
  __shared__ float Xs[64 * 65];
  const int tid = threadIdx.x;
  const int r0 = blockIdx.x * 64;
  const int b = r0 >> 11, kr0 = r0 & (NN - 1);
#pragma unroll
  for (int it = 0; it < 16; ++it) {                  // stage X tile (coalesced)
    int idx = it * 256 + tid;                        // 0..4095
    Xs[(idx >> 6) * 65 + (idx & 63)] = X[(size_t)r0 * DD + idx];
  }
  __syncthreads();
  const int wq = __builtin_amdgcn_readfirstlane(tid >> 6);
  const int lane = tid & 63;
  const int row = r0 + lane;
  float acc[16];
#pragma unroll
  for (int c = 0; c < 16; ++c) acc[c] = 0.f;
  const float* Xr = Xs + lane * 65;
  const float* W1p = W1 + wq * 16;
#pragma unroll
  for (int k = 0; k < 64; ++k) {
    const float xv = Xr[k];
#pragma unroll
    for (int c = 0; c < 16; ++c) acc[c] += xv * W1p[k * DD + c];  // s_loads
  }
  const float dv = dis[row];
#pragma unroll
  for (int c = 0; c < 16; ++c) acc[c] *= dv;
  // row-major bf16 (for epi1 diag term)
#pragma unroll
  for (int q = 0; q < 4; ++q) {
    u16x4 p = { f2bf(acc[q*4]), f2bf(acc[q*4+1]), f2bf(acc[q*4+2]), f2bf(acc[q*4+3]) };
    *(u16x4*)(Y1s + (size_t)row * DD + wq * 16 + q * 4) = p;
  }
  // transposed bf16 (B-operand layout for gemm1): Y1sT[b][n][k]
#pragma unroll
  for (int it = 0; it < 16; ++it)
    Y1sT[((size_t)b * DD + wq * 16 + it) * NN + kr0 + lane] = f2bf(acc[it]);
}

// ---- k_gemm1: Z1[ks] = Abf @ Y1 (bf16 MFMA 16x16x32), KS=4 ---------------
// wave: 2 M-tiles x 4 N-tiles; block: 4 waves = 128 rows.
__global__ __launch_bounds__(256) void k_gemm1(const unsigned short* __restrict__ Abf,
    const unsigned short* __restrict__ Y1sT, float* __restrict__ Z1)
{
  const int Mb = blockIdx.x >> 2, ks = blockIdx.x & 3;
  const int w = __builtin_amdgcn_readfirstlane((int)threadIdx.x >> 6);
  const int lane = threadIdx.x & 63;
  const int m15 = lane & 15, quad = lane >> 4;
  const int b = Mb >> 4;                       // 16 blocks per batch
  const int k0 = ks * 512 + quad * 8;
  const unsigned short* Ap0 = Abf + ((size_t)Mb * 128 + w * 16 + m15) * NN + k0;
  const unsigned short* Ap1 = Ap0 + (size_t)64 * NN;
  const unsigned short* Bp  = Y1sT + ((size_t)b * DD + m15) * NN + k0;
  const f32x4 zero = 0.f;
  f32x4 acc[2][4];
#pragma unroll
  for (int m = 0; m < 2; ++m)
#pragma unroll
    for (int t = 0; t < 4; ++t) acc[m][t] = zero;
  bf16x8 a0 = *(const bf16x8*)Ap0;
  bf16x8 a1 = *(const bf16x8*)Ap1;
  bf16x8 b0 = *(const bf16x8*)(Bp);
  bf16x8 b1 = *(const bf16x8*)(Bp + 16 * NN);
  bf16x8 b2 = *(const bf16x8*)(Bp + 32 * NN);
  bf16x8 b3 = *(const bf16x8*)(Bp + 48 * NN);
  for (int kk = 0; kk < 16; ++kk) {
    const int off = (kk < 15) ? (kk + 1) * 32 : 0;   // wrap: harmless re-read
    bf16x8 na0 = *(const bf16x8*)(Ap0 + off);
    bf16x8 na1 = *(const bf16x8*)(Ap1 + off);
    bf16x8 nb0 = *(const bf16x8*)(Bp + off);
    bf16x8 nb1 = *(const bf16x8*)(Bp + 16 * NN + off);
    bf16x8 nb2 = *(const bf16x8*)(Bp + 32 * NN + off);
    bf16x8 nb3 = *(const bf16x8*)(Bp + 48 * NN + off);
    acc[0][0] = mfma16(a0, b0, acc[0][0]);
    acc[0][1] = mfma16(a0, b1, acc[0][1]);
    acc[0][2] = mfma16(a0, b2, acc[0][2]);
    acc[0][3] = mfma16(a0, b3, acc[0][3]);
    acc[1][0] = mfma16(a1, b0, acc[1][0]);
    acc[1][1] = mfma16(a1, b1, acc[1][1]);
    acc[1][2] = mfma16(a1, b2, acc[1][2]);
    acc[1][3] = mfma16(a1, b3, acc[1][3]);
    a0 = na0; a1 = na1; b0 = nb0; b1 = nb1; b2 = nb2; b3 = nb3;
  }
  const int rb0 = Mb * 128 + w * 16 + quad * 4;      // D: row=quad*4+reg, col=lane&15
#pragma unroll
  for (int m = 0; m < 2; ++m)
#pragma unroll
    for (int t = 0; t < 4; ++t)
#pragma unroll
      for (int r = 0; r < 4; ++r)
        Z1[((size_t)ks * BN + rb0 + m * 64 + r) * DD + t * 16 + m15] = acc[m][t][r];
}

// ---- k_epi1: h = dropout(relu(dis*z+b1)); Y2 = dis*(h@W2) -> Y2sT bf16 ---
__global__ __launch_bounds__(256) void k_epi1(const float* __restrict__ Z1,
    const unsigned short* __restrict__ Y1s, const float* __restrict__ dis,
    const float* __restrict__ b1, const float* __restrict__ W2,
    unsigned short* __restrict__ Y2sT)
{
  __shared__ float hs[64 * 65];
  __shared__ float W2l[DD * CC];
  const int tid = threadIdx.x;
  const int r0 = blockIdx.x * 64;
  const int b = r0 >> 11, kr0 = r0 & (NN - 1);
  *(float4*)(W2l + tid * 4) = *(const float4*)(W2 + tid * 4);   // 1024 floats
  const int n = tid & 63, wg = tid >> 6;
  const float bias = b1[n];
#pragma unroll
  for (int i = 0; i < 16; ++i) {
    const int rl = wg * 16 + i;
    const size_t row = (size_t)r0 + rl;
    const size_t o = row * DD + n;
    float z = bf2f(Y1s[o]);                          // diag (self-loop) term
#pragma unroll
    for (int p = 0; p < 4; ++p) z += Z1[((size_t)p * BN + row) * DD + n];
    float h = fmaxf(dis[row] * z + bias, 0.f);
    const unsigned bits = tf_bits((unsigned)o);
    h = (bits >> 31) ? 0.f : (h + h);                // p=0.5, scale 2
    hs[rl * 65 + n] = h;
  }
  __syncthreads();
  const int c = tid & 15, rg = tid >> 4;             // 16 cols x 16 row-groups
  float y[4];
#pragma unroll
  for (int rr = 0; rr < 4; ++rr) {
    const int rl = rg * 4 + rr;
    float s = 0.f;
#pragma unroll
    for (int k = 0; k < 64; ++k) s += hs[rl * 65 + k] * W2l[k * CC + c];
    y[rr] = dis[r0 + rl] * s;
  }
  u16x4 pk = { f2bf(y[0]), f2bf(y[1]), f2bf(y[2]), f2bf(y[3]) };
  *(u16x4*)(Y2sT + ((size_t)b * CC + c) * NN + kr0 + rg * 4) = pk;
}

// ---- k_gemm2: Z2[ks] = Abf @ Y2 (bf16 MFMA), KS=8 ------------------------
// wave: 4 M-tiles x 1 N-tile; block: 4 waves = 256 rows.
__global__ __launch_bounds__(256) void k_gemm2(const unsigned short* __restrict__ Abf,
    const unsigned short* __restrict__ Y2sT, float* __restrict__ Z2)
{
  const int Mb = blockIdx.x >> 3, ks = blockIdx.x & 7;
  const int w = __builtin_amdgcn_readfirstlane((int)threadIdx.x >> 6);
  const int lane = threadIdx.x & 63;
  const int m15 = lane & 15, quad = lane >> 4;
  const int b = Mb >> 3;                       // 8 blocks per batch
  const int k0 = ks * 256 + quad * 8;
  const unsigned short* Ap = Abf + ((size_t)Mb * 256 + w * 16 + m15) * NN + k0;
  const unsigned short* Bp = Y2sT + ((size_t)b * CC + m15) * NN + k0;
  const f32x4 zero = 0.f;
  f32x4 acc[4];
#pragma unroll
  for (int m = 0; m < 4; ++m) acc[m] = zero;
  bf16x8 a[4];
#pragma unroll
  for (int m = 0; m < 4; ++m) a[m] = *(const bf16x8*)(Ap + (size_t)m * 64 * NN);
  bf16x8 bb = *(const bf16x8*)Bp;
  for (int kk = 0; kk < 8; ++kk) {
    const int off = (kk < 7) ? (kk + 1) * 32 : 0;
    bf16x8 na[4];
#pragma unroll
    for (int m = 0; m < 4; ++m) na[m] = *(const bf16x8*)(Ap + (size_t)m * 64 * NN + off);
    bf16x8 nbb = *(const bf16x8*)(Bp + off);
#pragma unroll
    for (int m = 0; m < 4; ++m) acc[m] = mfma16(a[m], bb, acc[m]);
#pragma unroll
    for (int m = 0; m < 4; ++m) a[m] = na[m];
    bb = nbb;
  }
  const int rb0 = Mb * 256 + w * 16 + quad * 4;
#pragma unroll
  for (int m = 0; m < 4; ++m)
#pragma unroll
    for (int r = 0; r < 4; ++r)
      Z2[((size_t)ks * BN + rb0 + m * 64 + r) * CC + m15] = acc[m][r];
}

// ---- k_final: out = dis*(sum Z2p + Y2diag) + b2 --------------------------
__global__ __launch_bounds__(256) void k_final(const float* __restrict__ Z2,
    const unsigned short* __restrict__ Y2sT, const float* __restrict__ dis,
    const float* __restrict__ b2, float* __restrict__ out)
{
  const int r = blockIdx.x * 256 + threadIdx.x;
  const int b = r >> 11, kr = r & (NN - 1);
  float s[16];
#pragma unroll
  for (int c = 0; c < 16; ++c) s[c] = bf2f(Y2sT[((size_t)b * CC + c) * NN + kr]);
#pragma unroll
  for (int p = 0; p < 8; ++p)
#pragma unroll
    for (int q = 0; q < 4; ++q) {
      float4 v = *(const float4*)(Z2 + ((size_t)p * BN + r) * CC + q * 4);
      s[q*4+0] += v.x; s[q*4+1] += v.y; s[q*4+2] += v.z; s[q*4+3] += v.w;
    }
  const float dv = dis[r];
#pragma unroll
  for (int q = 0; q < 4; ++q) {
    float4 o4;
    o4.x = dv * s[q*4+0] + b2[q*4+0];
    o4.y = dv * s[q*4+1] + b2[q*4+1];
    o4.z = dv * s[q*4+2] + b2[q*4+2];
    o4.w = dv * s[q*4+3] + b2[q*4+3];
    *(float4*)(out + (size_t)r * CC + q * 4) = o4;
  }
}

// ==================== FALLBACK fp32 PATH (R3, proven) ====================
#define FKS1 4
#define FKS2 16

__global__ __launch_bounds__(256) void d_deg_xw(const float* __restrict__ A,
    const float* __restrict__ X, const float* __restrict__ W1,
    float* __restrict__ dis, float* __restrict__ Y1s)
{
  const int w = threadIdx.x >> 6, lane = threadIdx.x & 63;
  const int row = __builtin_amdgcn_readfirstlane(blockIdx.x * 4 + w);
  const float4* Arow = (const float4*)(A + (size_t)row * NN);
  float s = 0.f;
#pragma unroll
  for (int it = 0; it < 8; ++it) {
    float4 v = Arow[lane + 64 * it];
    s += v.x + v.y + v.z + v.w;
  }
#pragma unroll
  for (int m = 32; m; m >>= 1) s += __shfl_xor(s, m, 64);
  const float dv = 1.0f / sqrtf(s + 1.0f);
  if (lane == 0) dis[row] = dv;
  const float* Xr = X + (size_t)row * DD;
  float acc = 0.f;
#pragma unroll
  for (int k = 0; k < DD; ++k) acc += Xr[k] * W1[k * DD + lane];
  Y1s[(size_t)row * DD + lane] = dv * acc;
}

__global__ __launch_bounds__(256) void d_gemm1(const float* __restrict__ A,
    const float* __restrict__ Y1s, float* __restrict__ Z1)
{
  const int rb = blockIdx.x >> 2, ks = blockIdx.x & (FKS1 - 1);
  const int lane = threadIdx.x & 63;
  const int c0 = __builtin_amdgcn_readfirstlane((threadIdx.x >> 6) << 4);
  const int row = rb * 64 + lane;
  const int batch = rb >> 5;
  const int KSEG = NN / FKS1;
  const float* Arow = A + (size_t)row * NN + ks * KSEG;
  const float* Yb = Y1s + (size_t)batch * NN * DD + c0;
  const int kbase = ks * KSEG;
  float acc[16];
#pragma unroll
  for (int c = 0; c < 16; ++c) acc[c] = 0.f;
  float4 a0 = *(const float4*)(Arow);
  float4 a1 = *(const float4*)(Arow + 4);
  float4 a2 = *(const float4*)(Arow + 8);
  float4 a3 = *(const float4*)(Arow + 12);
  for (int k = 0; k < KSEG; k += 16) {
    const int kn = (k + 16 < KSEG) ? (k + 16) : 0;
    float4 n0 = *(const float4*)(Arow + kn);
    float4 n1 = *(const float4*)(Arow + kn + 4);
    float4 n2 = *(const float4*)(Arow + kn + 8);
    float4 n3 = *(const float4*)(Arow + kn + 12);
    const float* y0 = Yb + (size_t)(kbase + k) * DD;
    const float av[16] = {a0.x, a0.y, a0.z, a0.w, a1.x, a1.y, a1.z, a1.w,
                          a2.x, a2.y, a2.z, a2.w, a3.x, a3.y, a3.z, a3.w};
#pragma unroll
    for (int j = 0; j < 16; ++j) {
      const float* yr = y0 + j * DD;
#pragma unroll
      for (int c = 0; c < 16; ++c) acc[c] += av[j] * yr[c];
    }
    a0 = n0; a1 = n1; a2 = n2; a3 = n3;
  }
  float* Zp = Z1 + ((size_t)ks * BN + row) * DD + c0;
#pragma unroll
  for (int c = 0; c < 16; c += 4) {
    float4 v; v.x = acc[c]; v.y = acc[c+1]; v.z = acc[c+2]; v.w = acc[c+3];
    *(float4*)(Zp + c) = v;
  }
}

__global__ __launch_bounds__(256) void d_epi1(const float* __restrict__ Z1,
    const float* __restrict__ Y1s, const float* __restrict__ dis,
    const float* __restrict__ b1, const float* __restrict__ W2,
    float* __restrict__ Y2s)
{
  __shared__ float W2l[DD * CC];
  __shared__ float hl[4][DD];
  const int tid = threadIdx.x;
  *(float4*)(W2l + tid * 4) = *(const float4*)(W2 + tid * 4);
  const int w = tid >> 6, lane = tid & 63;
  const int row = blockIdx.x * 4 + w;
  const size_t o = (size_t)row * DD + lane;
  float z = Y1s[o];
#pragma unroll
  for (int p = 0; p < FKS1; ++p) z += Z1[(size_t)p * BN * DD + o];
  const float dv = dis[row];
  float h = fmaxf(dv * z + b1[lane], 0.f);
  const unsigned bits = tf_bits((unsigned)o);
  h = (bits >> 31) ? 0.f : (h + h);
  hl[w][lane] = h;
  __syncthreads();
  const int wr = tid >> 6, l = tid & 63;
  const int c = l & 15, kq = l >> 4;
  float p = 0.f;
#pragma unroll
  for (int kk = 0; kk < 16; ++kk)
    p += hl[wr][kq * 16 + kk] * W2l[(kq * 16 + kk) * CC + c];
  p += __shfl_xor(p, 16, 64);
  p += __shfl_xor(p, 32, 64);
  if (l < 16) {
    const int rg = blockIdx.x * 4 + wr;
    Y2s[(size_t)rg * CC + c] = dis[rg] * p;
  }
}

__global__ __launch_bounds__(256) void d_gemm2(const float* __restrict__ A,
    const float* __restrict__ Y2s, float* __restrict__ Z2)
{
  const int rb = blockIdx.x >> 4, ks = blockIdx.x & (FKS2 - 1);
  const int row = rb * 256 + threadIdx.x;
  const int batch = rb >> 3;
  const int KSEG = NN / FKS2;
  const float* Arow = A + (size_t)row * NN + ks * KSEG;
  const float* Yb = Y2s + (size_t)batch * NN * CC;
  const int kbase = ks * KSEG;
  float acc[16];
#pragma unroll
  for (int c = 0; c < 16; ++c) acc[c] = 0.f;
  float4 a0 = *(const float4*)(Arow);
  float4 a1 = *(const float4*)(Arow + 4);
  for (int k = 0; k < KSEG; k += 8) {
    const int kn = (k + 8 < KSEG) ? (k + 8) : 0;
    float4 n0 = *(const float4*)(Arow + kn);
    float4 n1 = *(const float4*)(Arow + kn + 4);
    const float av[8] = {a0.x, a0.y, a0.z, a0.w, a1.x, a1.y, a1.z, a1.w};
#pragma unroll
    for (int j = 0; j < 8; ++j) {
      const float* yr = Yb + (size_t)(kbase + k + j) * CC;
#pragma unroll
      for (int c = 0; c < 16; ++c) acc[c] += av[j] * yr[c];
    }
    a0 = n0; a1 = n1;
  }
  float* Zp = Z2 + ((size_t)ks * BN + row) * CC;
#pragma unroll
  for (int c = 0; c < 16; c += 4) {
    float4 v; v.x = acc[c]; v.y = acc[c+1]; v.z = acc[c+2]; v.w = acc[c+3];
    *(float4*)(Zp + c) = v;
  }
}

__global__ __launch_bounds__(256) void d_final(const float* __restrict__ Z2,
    const float* __restrict__ Y2s, const float* __restrict__ dis,
    const float* __restrict__ b2, float* __restrict__ out)
{
  const int gid = blockIdx.x * 256 + threadIdx.x;
  const int r = gid >> 2, q = gid & 3;
  const size_t o = (size_t)r * CC + q * 4;
  float4 s = *(const float4*)(Y2s + o);
#pragma unroll
  for (int p = 0; p < FKS2; ++p) {
    const float4 zp = *(const float4*)(Z2 + (size_t)p * BN * CC + o);
    s.x += zp.x; s.y += zp.y; s.z += zp.z; s.w += zp.w;
  }
  const float dv = dis[r];
  const float4 bb = *(const float4*)(b2 + q * 4);
  float4 res;
  res.x = dv * s.x + bb.x;
  res.y = dv * s.y + bb.y;
  res.z = dv * s.z + bb.z;
  res.w = dv * s.w + bb.w;
  *(float4*)(out + o) = res;
}

extern "C" void kernel_launch(void* const* d_in, const int* in_sizes, int n_in,
                              void* d_out, int out_size, void* d_ws, size_t ws_size,
                              hipStream_t stream) {
  const float* X  = (const float*)d_in[0];
  const float* A  = (const float*)d_in[1];
  const float* W1 = (const float*)d_in[2];
  const float* b1 = (const float*)d_in[3];
  const float* W2 = (const float*)d_in[4];
  const float* b2 = (const float*)d_in[5];
  float* out = (float*)d_out;
  char* wsb = (char*)d_ws;

  // new-path ws layout (bytes): Abf 64MB | Z1 16MB (Z2 aliases) | dis 64KB |
  // Y1s 2MB | Y1sT 2MB | Y2sT 0.5MB  => 88,670,208 total
  const size_t NEED = 88670208;
  if (ws_size >= NEED) {
    unsigned short* Abf  = (unsigned short*)wsb;
    float*          Z1   = (float*)(wsb + 67108864);
    float*          Z2   = Z1;                          // aliases (Z1 dead)
    float*          dis  = (float*)(wsb + 83886080);
    unsigned short* Y1s  = (unsigned short*)(wsb + 83951616);
    unsigned short* Y1sT = (unsigned short*)(wsb + 86048768);
    unsigned short* Y2sT = (unsigned short*)(wsb + 88145920);

    k_deg  <<<BN / 4, 256, 0, stream>>>(A, dis, Abf);
    k_xw1  <<<BN / 64, 256, 0, stream>>>(X, W1, dis, Y1s, Y1sT);
    k_gemm1<<<512,    256, 0, stream>>>(Abf, Y1sT, Z1);
    k_epi1 <<<BN / 64, 256, 0, stream>>>(Z1, Y1s, dis, b1, W2, Y2sT);
    k_gemm2<<<512,    256, 0, stream>>>(Abf, Y2sT, Z2);
    k_final<<<BN / 256, 256, 0, stream>>>(Z2, Y2sT, dis, b2, out);
  } else {
    // fallback: proven fp32 path (R3)
    float* ws  = (float*)d_ws;
    float* dis = ws;
    float* Y1s = ws + 16384;
    float* Z1  = Y1s + (size_t)BN * DD;
    float* Z2  = Z1;
    float* Y2s = Z1 + (size_t)FKS1 * BN * DD;

    d_deg_xw<<<BN / 4,     256, 0, stream>>>(A, X, W1, dis, Y1s);
    d_gemm1 <<<256 * FKS1, 256, 0, stream>>>(A, Y1s, Z1);
    d_epi1  <<<BN / 4,     256, 0, stream>>>(Z1, Y1s, dis, b1, W2, Y2s);
    d_gemm2 <<<64 * FKS2,  256, 0, stream>>>(A, Y2s, Z2);
    d_final <<<256,        256, 0, stream>>>(Z2, Y2s, dis, b2, out);
  }
}